// Round 9
// baseline (133.335 us; speedup 1.0000x reference)
//
#include <hip/hip_runtime.h>
#include <cstdint>

#define NB 128
#define NT 1024
#define NC 128
#define NL 128
#define NS 257
#define EPSF 1e-7f
#define LN2F 0.69314718055994530942f
#define NEGL2 -1.442695e30f   // *ln2 ~= -1e30 (reference NEG)

typedef float __attribute__((ext_vector_type(2))) v2f;

__device__ __forceinline__ float fexp2(float x){ return __builtin_amdgcn_exp2f(x); }
__device__ __forceinline__ float flog2(float x){ return __builtin_amdgcn_logf(x); }

// Wave shift-up-by-1 in the VALU pipe: v_mov_b32_dpp wave_shr:1 (ctrl 0x138),
// bound_ctrl=1 -> lane 0 receives 0. All call sites are lane-0-safe.
__device__ __forceinline__ float shup1(float x){
    int r = __builtin_amdgcn_update_dpp(0, __float_as_int(x), 0x138, 0xf, 0xf, true);
    return __int_as_float(r);
}
__device__ __forceinline__ int shup1i(int x){
    return __builtin_amdgcn_update_dpp(0, x, 0x138, 0xf, 0xf, true);
}

// Async global->LDS DMA, 16 B/lane, wave-uniform LDS base (HW adds lane*16).
// Tracked by vmcnt; zero registers; issue cost only — off the serial chain.
__device__ __forceinline__ void dma16(const float* g, float* lds){
    __builtin_amdgcn_global_load_lds((const __attribute__((address_space(1))) void*)g,
                                     (__attribute__((address_space(3))) void*)lds,
                                     16, 0, 0);
}

// HW drain of DMA + compiler-level memory barrier (no load may cross).
#define VM_DRAIN() asm volatile("s_waitcnt vmcnt(0)" ::: "memory")

// LDS byte-offset of a __shared__ address (for raw ds_read asm).
#define AS3U(p) ((unsigned)(size_t)(__attribute__((address_space(3))) void*)(p))

// Hand-counted LDS wait + scheduling wall (rule #18: the sched_barrier stops
// the compiler hoisting dependent VALU between the ds_read asm and the wait).
#define WAITLGKM(N) do{ asm volatile("s_waitcnt lgkmcnt(" #N ")" ::: "memory"); \
                        __builtin_amdgcn_sched_barrier(0); }while(0)

// Pinned fill: 6x volatile ds_read2st64_b32 (st64 unit = 256 B; row stride
// 512 B = 2 units). Volatile asm cannot be reordered against other volatile
// asm, so these ISSUE here — two groups ahead of their consumer — and cannot
// be sunk to just-before-use by the scheduler (r5-confirmed: pinning these
// was worth 82->67.6 us). O0..O3 are st64 offsets for rows g*4+0..3.
// NOTE (r8 lesson): pinned asm is for the MEMORY schedule only; the COMPUTE
// must stay plain C so the scheduler can interleave it (r8's asm pk_* in the
// step regressed 53.5->70.8 us).
#define FILLA(S, O0,O1,O2,O3) do{ \
  asm volatile("ds_read2st64_b32 %0, %1 offset0:" #O0 " offset1:" #O1 : "=v"(S##B2[0]) : "v"(aB)); \
  asm volatile("ds_read2st64_b32 %0, %1 offset0:" #O2 " offset1:" #O3 : "=v"(S##B2[1]) : "v"(aB)); \
  asm volatile("ds_read2st64_b32 %0, %1 offset0:" #O0 " offset1:" #O1 : "=v"(S##A2[0]) : "v"(aA)); \
  asm volatile("ds_read2st64_b32 %0, %1 offset0:" #O2 " offset1:" #O3 : "=v"(S##A2[1]) : "v"(aA)); \
  asm volatile("ds_read2st64_b32 %0, %1 offset0:" #O0 " offset1:" #O1 : "=v"(S##C2[0]) : "v"(aC)); \
  asm volatile("ds_read2st64_b32 %0, %1 offset0:" #O2 " offset1:" #O3 : "=v"(S##C2[1]) : "v"(aC)); \
}while(0)

// 4 steps consuming bank S. EPS is applied as packed v2f adds on the fill
// pairs (plain C vector add — compiler emits it well). freeze only for the
// single partial chunk.
#define GROUP(S, gg) do{ \
    const v2f pb0 = S##B2[0] + E2, pa0 = S##A2[0] + E2, pc0 = S##C2[0] + E2; \
    const v2f pb1 = S##B2[1] + E2, pa1 = S##A2[1] + E2, pc1 = S##C2[1] + E2; \
    { const bool c_ = !freeze || ((k*32 + (gg)*4 + 0) < Tn); step1(pb0.x, pa0.x, pc0.x, c_); } \
    shm3 = shup1(m3); \
    { const bool c_ = !freeze || ((k*32 + (gg)*4 + 1) < Tn); step1(pb0.y, pa0.y, pc0.y, c_); } \
    shm3 = shup1(m3); \
    { const bool c_ = !freeze || ((k*32 + (gg)*4 + 2) < Tn); step1(pb1.x, pa1.x, pc1.x, c_); } \
    shm3 = shup1(m3); \
    { const bool c_ = !freeze || ((k*32 + (gg)*4 + 3) < Tn); step1(pb1.y, pa1.y, pc1.y, c_); } \
    boundary(early); }while(0)

// One wave per batch. Lane l owns extended states 4l..4l+3 (lane 63 also 256).
// alpha = m * 2^e, exact pow2 rescale every 4 steps (r6-validated math).
// e is INT; f0 = 2^d bit-constructed (bit-identical to fexp2 of integral arg).
__global__ __launch_bounds__(64,1)
void ctc_fwd_kernel(const int* __restrict__ y_true,
                    const float* __restrict__ y_pred,
                    const int* __restrict__ input_len,
                    const int* __restrict__ label_len,
                    float* __restrict__ out)
{
    __shared__ float buf[2][32 * NC];   // 2 x 16 KB double-buffered prob rows
    __shared__ float lg_alpha[NS + 3];

    const int b    = blockIdx.x;
    const int lane = threadIdx.x;
    const float* __restrict__ base = y_pred + (size_t)b * NT * NC;

    int Tn = input_len[b];
    Tn = Tn < 0 ? 0 : (Tn > NT ? NT : Tn);   // setup guarantees Tn in [512,1024]

    const int* __restrict__ yrow = y_true + b * NL;
    const int y0v = yrow[2 * lane]     & (NC - 1);   // label for state 4l+1
    const int y1v = yrow[2 * lane + 1] & (NC - 1);   // label for state 4l+3
    const int yp  = shup1i(y1v);                     // y[2l-1] (lane0: unused)
    const bool skip1 = (lane > 0) && (y0v != yp);
    const bool skip3 = (y1v != y0v);
    const bool isl0  = (lane == 0);
    const bool isl63 = (lane == 63);
    const float skip3f = skip3 ? 1.f : 0.f;  // exact {0,1} multiplier for t3

    const v2f E2 = { EPSF, EPSF };

    float m0 = isl0 ? 1.f : 0.f, m1 = 0.f, m2 = 0.f, m3 = 0.f, m4 = 0.f;
    int   ei  = 0;                // per-lane log2 scale (exact integer)
    float f0  = isl0 ? 0.f : 1.f; // neighbor->self scale factor (per group)
    float fs1 = skip1 ? f0 : 0.f;
    float shm3 = 0.f;             // neighbor's m3 (prev step), own scale

    // three rotating register banks: one 4-step group of p-value pairs each
    v2f s0B2[2], s0A2[2], s0C2[2];
    v2f s1B2[2], s1A2[2], s1C2[2];
    v2f s2B2[2], s2A2[2], s2C2[2];

    auto dma_chunk = [&](int c){              // stage chunk c into buf[c&1]
        const float* gsrc = base + (size_t)c * 32 * NC;
        float* dst = &buf[c & 1][0];
        #pragma unroll
        for (int i = 0; i < 16; ++i)
            dma16(gsrc + i * 256 + lane * 4, dst + i * 256);
    };

    // Per-step transition. fmaf choices are bit-safe:
    //  a6: product m1*skip3f is EXACT ({0,1} multiplier) -> fma == cnd+add.
    //  a7/a4: single-use mul+add chains the compiler already contracts under
    //  -ffp-contract=fast; written explicitly to drop the separate muls.
    auto step1 = [&](float Pb, float Pa, float Pc, bool commit){
        float a1  = m3 + m2;
        float a2  = m2 + m1;
        float s43 = m4 + m3;
        float a5  = m1 + m0;
        float a6  = fmaf(m1,   skip3f, a1);   // a1 + (skip3 ? m1 : 0)
        float a7  = fmaf(shm3, fs1,    a5);   // a5 + shm3*fs1
        float a4  = fmaf(shm3, f0,     m0);   // m0 + shm3*f0
        float n3 = Pc * a6;
        float n2 = Pb * a2;
        float n4 = Pb * s43;
        float n0 = Pb * a4;
        float n1 = Pa * a7;
        if (commit) { m0 = n0; m1 = n1; m2 = n2; m3 = n3; m4 = n4; }
    };

    auto boundary = [&](bool early){
        float mx = fmaxf(fmaxf(m0, m1), fmaxf(m2, m3));
        if (isl63) mx = fmaxf(mx, m4);
        const uint32_t bx = __float_as_uint(mx);
        const int eb = (int)(bx >> 23);
        const float inv = __uint_as_float((uint32_t)(254 - eb) << 23); // exact 2^-ef
        const int de = eb - 127;
        int s_nb;
        if (early) {
            // two-pass scale adoption while the reachability front propagates
            const bool dead = (mx == 0.f);
            int e1 = dead ? ei : (ei + de);
            int s1 = shup1i(e1);
            int e2 = (dead && !isl0) ? s1 : e1;
            int s2 = shup1i(e2);
            ei = (dead && !isl0) ? s2 : e2;
            s_nb = s2;
        } else {
            // k>=8 (t>=256): the front has covered all 257 states and p>=EPS
            // keeps every reached m strictly positive -> no dead lanes
            // (validated bit-exact in the r8 run, absmax 0.0).
            ei += de;
            s_nb = shup1i(ei);
        }
        int d = s_nb - ei;
        d = d < -126 ? -126 : (d > 126 ? 126 : d);
        // 2^d, d integer in [-126,126]: exact bit construction (== fexp2(d))
        f0 = isl0 ? 0.f : __uint_as_float((uint32_t)(d + 127) << 23);
        fs1 = skip1 ? f0 : 0.f;
        m0 *= inv; m1 *= inv; m2 *= inv; m3 *= inv; m4 *= inv;
        shm3 = shup1(m3);                      // post-rescale, matches new f0
    };

    auto chunkbody = [&](int k, bool early, bool freeze){
        const int h = k & 1;
        const unsigned aB = AS3U(&buf[h][NC - 1]);   // blank prob (uniform addr)
        const unsigned aA = AS3U(&buf[h][y0v]);      // label prob, state 4l+1
        const unsigned aC = AS3U(&buf[h][y1v]);      // label prob, state 4l+3

        FILLA(s0,  0, 2, 4, 6);           // group 0 (chunk k already drained)
        if (k + 1 < 32) dma_chunk(k + 1); // stage next chunk (other half)
        FILLA(s1,  8,10,12,14);           // group 1 — 2-deep from the start

        // steady state: every use waits only past the 2 newer in-flight fills
        FILLA(s2, 16,18,20,22); WAITLGKM(12); GROUP(s0, 0);
        FILLA(s0, 24,26,28,30); WAITLGKM(12); GROUP(s1, 1);
        FILLA(s1, 32,34,36,38); WAITLGKM(12); GROUP(s2, 2);
        FILLA(s2, 40,42,44,46); WAITLGKM(12); GROUP(s0, 3);
        FILLA(s0, 48,50,52,54); WAITLGKM(12); GROUP(s1, 4);
        FILLA(s1, 56,58,60,62); WAITLGKM(12); GROUP(s2, 5);
                                WAITLGKM(6);  GROUP(s0, 6);
                                WAITLGKM(0);  GROUP(s1, 7);

        VM_DRAIN();   // next chunk's DMA complete; barrier for the compiler too
    };

    // prologue: stage chunk 0, drain
    dma_chunk(0);
    VM_DRAIN();

    // Tn in [512,1024] wave-uniform. Chunks < nfull are fully active (no
    // per-step predication); at most ONE partial chunk keeps the cndmask
    // path; chunks past Tn are exact no-ops (post-rescale max is in [1,2) so
    // inv=1, ef=0, f0/fs1/shm3 recompute identically) -> skip them, bit-exact.
    const int nfull = Tn >> 5;                // >= 16
    #pragma unroll 1
    for (int k = 0; k < 8; ++k)       chunkbody(k, true,  false);
    #pragma unroll 1
    for (int k = 8; k < nfull; ++k)   chunkbody(k, false, false);
    if (nfull < 32 && (Tn & 31))      chunkbody(nfull, false, true);

    // ---- epilogue ----
    const float e = (float)ei;                // exact int->float
    lg_alpha[4 * lane + 0] = (m0 > 0.f) ? (e + flog2(m0)) : NEGL2;
    lg_alpha[4 * lane + 1] = (m1 > 0.f) ? (e + flog2(m1)) : NEGL2;
    lg_alpha[4 * lane + 2] = (m2 > 0.f) ? (e + flog2(m2)) : NEGL2;
    lg_alpha[4 * lane + 3] = (m3 > 0.f) ? (e + flog2(m3)) : NEGL2;
    if (isl63) lg_alpha[256] = (m4 > 0.f) ? (e + flog2(m4)) : NEGL2;
    __syncthreads();

    if (lane == 0) {
        int lab = label_len[b];
        lab = lab < 0 ? 0 : (lab > NL ? NL : lab);
        const int i_last = 2 * lab;
        const int i_prev = i_last > 0 ? i_last - 1 : 0;
        float A  = lg_alpha[i_last];
        float Bv = lg_alpha[i_prev];
        float mx = fmaxf(A, Bv);
        float r;
        if (mx < -1.0e29f) {
            r = mx;
        } else {
            float s = fexp2(A - mx) + fexp2(Bv - mx);
            r = mx + flog2(s);
        }
        out[b] = -r * LN2F;
    }
}

extern "C" void kernel_launch(void* const* d_in, const int* in_sizes, int n_in,
                              void* d_out, int out_size, void* d_ws, size_t ws_size,
                              hipStream_t stream) {
    const int*   y_true    = (const int*)d_in[0];
    const float* y_pred    = (const float*)d_in[1];
    const int*   input_len = (const int*)d_in[2];
    const int*   label_len = (const int*)d_in[3];
    float* outp = (float*)d_out;
    ctc_fwd_kernel<<<dim3(NB), dim3(64), 0, stream>>>(y_true, y_pred, input_len, label_len, outp);
}

// Round 10
// 128.954 us; speedup vs baseline: 1.0340x; 1.0340x over previous
//
#include <hip/hip_runtime.h>
#include <cstdint>

#define NB 128
#define NT 1024
#define NC 128
#define NL 128
#define NS 257
#define EPSF 1e-7f
#define LN2F 0.69314718055994530942f
#define NEGL2 -1.442695e30f   // *ln2 ~= -1e30 (reference NEG)

typedef float __attribute__((ext_vector_type(2))) v2f;
typedef float __attribute__((ext_vector_type(4))) v4f;

__device__ __forceinline__ float fexp2(float x){ return __builtin_amdgcn_exp2f(x); }
__device__ __forceinline__ float flog2(float x){ return __builtin_amdgcn_logf(x); }

// Wave shift-up-by-1 in the VALU pipe: v_mov_b32_dpp wave_shr:1 (ctrl 0x138),
// bound_ctrl=1 -> lane 0 receives 0. All call sites are lane-0-safe.
__device__ __forceinline__ float shup1(float x){
    int r = __builtin_amdgcn_update_dpp(0, __float_as_int(x), 0x138, 0xf, 0xf, true);
    return __int_as_float(r);
}
__device__ __forceinline__ int shup1i(int x){
    return __builtin_amdgcn_update_dpp(0, x, 0x138, 0xf, 0xf, true);
}

// Async global->LDS DMA, 16 B/lane, wave-uniform LDS base (HW adds lane*16).
__device__ __forceinline__ void dma16(const float* g, float* lds){
    __builtin_amdgcn_global_load_lds((const __attribute__((address_space(1))) void*)g,
                                     (__attribute__((address_space(3))) void*)lds,
                                     16, 0, 0);
}

#define VM_DRAIN() asm volatile("s_waitcnt vmcnt(0)" ::: "memory")

// LDS byte-offset of a __shared__ address (for raw ds_read asm).
#define AS3U(p) ((unsigned)(size_t)(__attribute__((address_space(3))) void*)(p))

// Hand-counted LDS wait + scheduling wall (rule #18).
#define WAITLGKM(N) do{ asm volatile("s_waitcnt lgkmcnt(" #N ")" ::: "memory"); \
                        __builtin_amdgcn_sched_barrier(0); }while(0)

// Workgroup barrier as volatile asm: ordered against the volatile FILLA asm
// and carries a compiler memory fence. Consumer form (no pending ds_writes).
#define BAR_C() asm volatile("s_barrier" ::: "memory")
// Producer form: drain its eps-pass ds_writes first so the image is visible.
#define BAR_P() asm volatile("s_waitcnt lgkmcnt(0)\n\ts_barrier" ::: "memory")

// Pinned fill: 6x volatile ds_read2st64_b32 (st64 unit = 256 B; row stride
// 512 B = 2 units), issued two groups ahead of use (r5: 82->67.6 us win).
// r8 lesson: pinned asm is for the MEMORY schedule only; compute stays C.
#define FILLA(S, O0,O1,O2,O3) do{ \
  asm volatile("ds_read2st64_b32 %0, %1 offset0:" #O0 " offset1:" #O1 : "=v"(S##B2[0]) : "v"(aB)); \
  asm volatile("ds_read2st64_b32 %0, %1 offset0:" #O2 " offset1:" #O3 : "=v"(S##B2[1]) : "v"(aB)); \
  asm volatile("ds_read2st64_b32 %0, %1 offset0:" #O0 " offset1:" #O1 : "=v"(S##A2[0]) : "v"(aA)); \
  asm volatile("ds_read2st64_b32 %0, %1 offset0:" #O2 " offset1:" #O3 : "=v"(S##A2[1]) : "v"(aA)); \
  asm volatile("ds_read2st64_b32 %0, %1 offset0:" #O0 " offset1:" #O1 : "=v"(S##C2[0]) : "v"(aC)); \
  asm volatile("ds_read2st64_b32 %0, %1 offset0:" #O2 " offset1:" #O3 : "=v"(S##C2[1]) : "v"(aC)); \
}while(0)

// 4 steps consuming bank S (img already has EPS pre-added by the producer).
#define GROUP(S, gg) do{ \
    { const bool c_ = !freeze || ((k*32 + (gg)*4 + 0) < Tn); step1(S##B2[0].x, S##A2[0].x, S##C2[0].x, c_); } \
    shm3 = shup1(m3); \
    { const bool c_ = !freeze || ((k*32 + (gg)*4 + 1) < Tn); step1(S##B2[0].y, S##A2[0].y, S##C2[0].y, c_); } \
    shm3 = shup1(m3); \
    { const bool c_ = !freeze || ((k*32 + (gg)*4 + 2) < Tn); step1(S##B2[1].x, S##A2[1].x, S##C2[1].x, c_); } \
    shm3 = shup1(m3); \
    { const bool c_ = !freeze || ((k*32 + (gg)*4 + 3) < Tn); step1(S##B2[1].y, S##A2[1].y, S##C2[1].y, c_); } \
    boundary(early); }while(0)

// Two waves per batch. Wave 1 = PRODUCER: DMA chunk -> raw, pre-add EPS into
// img (identical f32 add -> bit-exact), one chunk ahead. Wave 0 = CONSUMER:
// the pure recurrence — zero global-memory / eps instructions (r7/r9 model:
// wall = ~5.5 cyc x instr/step, so removing ~3 non-recurrence instr/step
// is the lever). One s_barrier per chunk; counts matched via CT on both.
__global__ __launch_bounds__(128,1)
void ctc_fwd_kernel(const int* __restrict__ y_true,
                    const float* __restrict__ y_pred,
                    const int* __restrict__ input_len,
                    const int* __restrict__ label_len,
                    float* __restrict__ out)
{
    __shared__ __align__(16) float raw[2][32 * NC];  // producer-private staging
    __shared__ __align__(16) float img[2][32 * NC];  // eps-added, consumer-read
    __shared__ float lg_alpha[NS + 3];

    const int b    = blockIdx.x;
    const int tid  = threadIdx.x;
    const int lane = tid & 63;

    int Tn = input_len[b];
    Tn = Tn < 0 ? 0 : (Tn > NT ? NT : Tn);   // setup guarantees Tn in [512,1024]
    const int nfull   = Tn >> 5;             // >= 16
    const int partial = (nfull < 32 && (Tn & 31)) ? 1 : 0;
    const int CT      = nfull + partial;     // chunks consumed; barriers per wave

    if (tid >= 64) {
        // ---------------- producer wave ----------------
        const float* __restrict__ base = y_pred + (size_t)b * NT * NC;
        auto dma_chunk = [&](int c){
            const float* gsrc = base + (size_t)c * 32 * NC;
            float* dst = &raw[c & 1][0];
            #pragma unroll
            for (int i = 0; i < 16; ++i)
                dma16(gsrc + i * 256 + lane * 4, dst + i * 256);
        };
        auto eps_pass = [&](int c){          // raw -> img with EPS pre-added
            const v4f* s = (const v4f*)&raw[c & 1][0];
            v4f*       d = (v4f*)&img[c & 1][0];
            #pragma unroll
            for (int j = 0; j < 16; ++j){
                v4f v = s[j * 64 + lane];
                v += (v4f){EPSF, EPSF, EPSF, EPSF};
                d[j * 64 + lane] = v;
            }
        };
        dma_chunk(0); VM_DRAIN(); eps_pass(0);
        dma_chunk(1);                        // CT >= 16 always
        #pragma unroll 1
        for (int k = 0; k < CT; ++k){
            BAR_P();                         // img[k&1] published to consumer
            if (k + 1 < CT){ VM_DRAIN(); eps_pass(k + 1); }
            if (k + 2 < CT) dma_chunk(k + 2);
        }
        return;
    }

    // ---------------- consumer wave ----------------
    const int* __restrict__ yrow = y_true + b * NL;
    const int y0v = yrow[2 * lane]     & (NC - 1);   // label for state 4l+1
    const int y1v = yrow[2 * lane + 1] & (NC - 1);   // label for state 4l+3
    const int yp  = shup1i(y1v);                     // y[2l-1] (lane0: unused)
    const bool skip1 = (lane > 0) && (y0v != yp);
    const bool skip3 = (y1v != y0v);
    const bool isl0  = (lane == 0);
    const bool isl63 = (lane == 63);
    const float skip3f = skip3 ? 1.f : 0.f;  // exact {0,1} multiplier for t3

    float m0 = isl0 ? 1.f : 0.f, m1 = 0.f, m2 = 0.f, m3 = 0.f, m4 = 0.f;
    int   ei  = 0;                // per-lane log2 scale (exact integer)
    // f0 on lane 0 only ever multiplies shm3 == 0 (DPP bound_ctrl) -> its
    // value is irrelevant there; the old isl0 cndmask was dead code.
    float f0  = 1.f;
    float fs1 = skip1 ? 1.f : 0.f;
    float shm3 = 0.f;             // neighbor's m3 (prev step), own scale

    // three rotating register banks: one 4-step group of p-value pairs each
    v2f s0B2[2], s0A2[2], s0C2[2];
    v2f s1B2[2], s1A2[2], s1C2[2];
    v2f s2B2[2], s2A2[2], s2C2[2];

    // Per-step transition. fmaf choices are bit-safe:
    //  a6: product m1*skip3f is EXACT ({0,1} multiplier) -> fma == cnd+add.
    //  a7/a4: single-use mul+add chains the compiler contracts anyway.
    auto step1 = [&](float Pb, float Pa, float Pc, bool commit){
        float a1  = m3 + m2;
        float a2  = m2 + m1;
        float s43 = m4 + m3;
        float a5  = m1 + m0;
        float a6  = fmaf(m1,   skip3f, a1);   // a1 + (skip3 ? m1 : 0)
        float a7  = fmaf(shm3, fs1,    a5);   // a5 + shm3*fs1
        float a4  = fmaf(shm3, f0,     m0);   // m0 + shm3*f0
        float n3 = Pc * a6;
        float n2 = Pb * a2;
        float n4 = Pb * s43;
        float n0 = Pb * a4;
        float n1 = Pa * a7;
        if (commit) { m0 = n0; m1 = n1; m2 = n2; m3 = n3; m4 = n4; }
    };

    auto boundary = [&](bool early){
        float mx = fmaxf(fmaxf(m0, m1), fmaxf(m2, m3));
        if (isl63) mx = fmaxf(mx, m4);
        const uint32_t bx = __float_as_uint(mx);
        const int eb = (int)(bx >> 23);
        const float inv = __uint_as_float((uint32_t)(254 - eb) << 23); // exact 2^-ef
        const int de = eb - 127;
        int s_nb;
        if (early) {
            // two-pass scale adoption while the reachability front propagates
            const bool dead = (mx == 0.f);
            int e1 = dead ? ei : (ei + de);
            int s1 = shup1i(e1);
            int e2 = (dead && !isl0) ? s1 : e1;
            int s2 = shup1i(e2);
            ei = (dead && !isl0) ? s2 : e2;
            s_nb = s2;
        } else {
            // k>=8 (t>=256): front covers all 257 states; p>=EPS keeps every
            // reached m > 0 -> no dead lanes (bit-exact validated r8/r9).
            ei += de;
            s_nb = shup1i(ei);
        }
        int d = s_nb - ei;
        d = d < -126 ? -126 : (d > 126 ? 126 : d);
        // 2^d, d integer in [-126,126]: exact bit construction (== fexp2(d))
        f0 = __uint_as_float((uint32_t)(d + 127) << 23);
        fs1 = skip1 ? f0 : 0.f;
        m0 *= inv; m1 *= inv; m2 *= inv; m3 *= inv; m4 *= inv;
        shm3 = shup1(m3);                      // post-rescale, matches new f0
    };

    auto chunkbody = [&](int k, bool early, bool freeze){
        const int h = k & 1;
        const unsigned aB = AS3U(&img[h][NC - 1]);   // blank prob (uniform addr)
        const unsigned aA = AS3U(&img[h][y0v]);      // label prob, state 4l+1
        const unsigned aC = AS3U(&img[h][y1v]);      // label prob, state 4l+3

        FILLA(s0,  0, 2, 4, 6);
        FILLA(s1,  8,10,12,14);           // 2-deep from the start

        FILLA(s2, 16,18,20,22); WAITLGKM(12); GROUP(s0, 0);
        FILLA(s0, 24,26,28,30); WAITLGKM(12); GROUP(s1, 1);
        FILLA(s1, 32,34,36,38); WAITLGKM(12); GROUP(s2, 2);
        FILLA(s2, 40,42,44,46); WAITLGKM(12); GROUP(s0, 3);
        FILLA(s0, 48,50,52,54); WAITLGKM(12); GROUP(s1, 4);
        FILLA(s1, 56,58,60,62); WAITLGKM(12); GROUP(s2, 5);
                                WAITLGKM(6);  GROUP(s0, 6);
                                WAITLGKM(0);  GROUP(s1, 7);
    };

    // Barrier pairing: consumer executes exactly CT barriers (one before each
    // consumed chunk); producer executes CT (one per loop epoch). Before the
    // consumer's chunk-k barrier releases, the producer has built img[k&1].
    #pragma unroll 1
    for (int k = 0; k < 8; ++k)      { BAR_C(); chunkbody(k, true,  false); }
    #pragma unroll 1
    for (int k = 8; k < nfull; ++k)  { BAR_C(); chunkbody(k, false, false); }
    if (partial)                     { BAR_C(); chunkbody(nfull, false, true); }

    // ---- epilogue (consumer-wave-local; lgkm drain orders write->read) ----
    const float e = (float)ei;                // exact int->float
    lg_alpha[4 * lane + 0] = (m0 > 0.f) ? (e + flog2(m0)) : NEGL2;
    lg_alpha[4 * lane + 1] = (m1 > 0.f) ? (e + flog2(m1)) : NEGL2;
    lg_alpha[4 * lane + 2] = (m2 > 0.f) ? (e + flog2(m2)) : NEGL2;
    lg_alpha[4 * lane + 3] = (m3 > 0.f) ? (e + flog2(m3)) : NEGL2;
    if (isl63) lg_alpha[256] = (m4 > 0.f) ? (e + flog2(m4)) : NEGL2;
    asm volatile("s_waitcnt lgkmcnt(0)" ::: "memory");

    if (lane == 0) {
        int lab = label_len[b];
        lab = lab < 0 ? 0 : (lab > NL ? NL : lab);
        const int i_last = 2 * lab;
        const int i_prev = i_last > 0 ? i_last - 1 : 0;
        float A  = lg_alpha[i_last];
        float Bv = lg_alpha[i_prev];
        float mx = fmaxf(A, Bv);
        float r;
        if (mx < -1.0e29f) {
            r = mx;
        } else {
            float s = fexp2(A - mx) + fexp2(Bv - mx);
            r = mx + flog2(s);
        }
        out[b] = -r * LN2F;
    }
}

extern "C" void kernel_launch(void* const* d_in, const int* in_sizes, int n_in,
                              void* d_out, int out_size, void* d_ws, size_t ws_size,
                              hipStream_t stream) {
    const int*   y_true    = (const int*)d_in[0];
    const float* y_pred    = (const float*)d_in[1];
    const int*   input_len = (const int*)d_in[2];
    const int*   label_len = (const int*)d_in[3];
    float* outp = (float*)d_out;
    ctc_fwd_kernel<<<dim3(NB), dim3(128), 0, stream>>>(y_true, y_pred, input_len, label_len, outp);
}